// Round 2
// 388.351 us; speedup vs baseline: 1.0122x; 1.0122x over previous
//
#include <hip/hip_runtime.h>
#include <hip/hip_bf16.h>

typedef __attribute__((ext_vector_type(8))) short short8;
typedef __attribute__((ext_vector_type(4))) float f32x4;

#define MFMA16(a, b, c) __builtin_amdgcn_mfma_f32_16x16x32_bf16((a), (b), (c), 0, 0, 0)

constexpr int B_ = 4;
constexpr int N_ = 4096;
constexpr int F_ = 512;
constexpr int HA_ = 128;
constexpr int HV_ = 32;

// ---------------- ws layout (bytes) ----------------
constexpr size_t OFF_WTA = 256;                            // Wt_act bf16 [128][512]
constexpr size_t OFF_WTV = OFF_WTA + (size_t)HA_ * F_ * 2; // Wt_v1  bf16 [32][512]
constexpr size_t OFF_HN  = OFF_WTV + (size_t)HV_ * F_ * 2; // hn bf16 [4][4096][128]

__device__ __forceinline__ short bf16bits(float x) {
  __hip_bfloat16 h = __float2bfloat16(x);
  return *reinterpret_cast<short*>(&h);
}

__device__ __forceinline__ short8 load_bf16x8(const float* p) {
  float4 f0 = *(const float4*)p;
  float4 f1 = *(const float4*)(p + 4);
  short8 r;
  r[0] = bf16bits(f0.x); r[1] = bf16bits(f0.y);
  r[2] = bf16bits(f0.z); r[3] = bf16bits(f0.w);
  r[4] = bf16bits(f1.x); r[5] = bf16bits(f1.y);
  r[6] = bf16bits(f1.z); r[7] = bf16bits(f1.w);
  return r;
}

// ---------------- transpose + bf16-convert W_act, W_v1 ----------------
__global__ __launch_bounds__(256) void k_tr(
    const float* __restrict__ W_act,      // [513][128] fp32
    const float* __restrict__ W_v1,       // [513][32] fp32
    __hip_bfloat16* __restrict__ wt_act,  // [128][512] bf16
    __hip_bfloat16* __restrict__ wt_v1)   // [32][512] bf16
{
  int idx = blockIdx.x * 256 + threadIdx.x;
  if (idx < F_ * HA_) {
    int n = idx >> 9, k = idx & 511;  // wt_act[n][k] <- W_act[k][n]
    wt_act[idx] = __float2bfloat16(W_act[(size_t)k * HA_ + n]);
  } else {
    int i2 = idx - F_ * HA_;
    if (i2 < F_ * HV_) {
      int n = i2 >> 9, k = i2 & 511;  // wt_v1[n][k] <- W_v1[k][n]
      wt_v1[i2] = __float2bfloat16(W_v1[(size_t)k * HV_ + n]);
    }
  }
}

// ---------------- h GEMM + normalize + critic ----------------
// grid: B * (N/64) blocks, 256 threads (4 waves); wave = 16 rows x 128 cols.
__global__ __launch_bounds__(256) void k_hn(
    const float* __restrict__ obs,         // [4][4096][512]
    const float* __restrict__ gen_number,  // [4][1]
    const float* __restrict__ W_gen,       // [1][1]
    const float* __restrict__ b_gen,       // [1]
    const float* __restrict__ W_act,       // [513][128] (row 512 = gen col)
    const float* __restrict__ b_act,       // [128]
    const float* __restrict__ W_v1,        // [513][32] (row 512 = gen col)
    const float* __restrict__ b_v1,        // [32]
    const float* __restrict__ W_v2,        // [32][1]
    const float* __restrict__ b_v2,        // [1]
    const __hip_bfloat16* __restrict__ wt_act,  // [128][512] bf16
    const __hip_bfloat16* __restrict__ wt_v1,   // [32][512] bf16
    __hip_bfloat16* __restrict__ hn,            // [4][4096][128] bf16
    float* __restrict__ critic_acc)             // [4]
{
  const int wave = threadIdx.x >> 6;
  const int lane = threadIdx.x & 63;
  const int q = lane >> 4;
  const int t16 = lane & 15;
  const int b = blockIdx.x >> 6;
  const int rblk = blockIdx.x & 63;
  const int r0 = rblk * 64 + wave * 16;

  float x = gen_number[b] * W_gen[0] + b_gen[0];
  const float gen = x > 0.f ? x : 0.01f * x;

  f32x4 acc[8];
  f32x4 accv[2];
#pragma unroll
  for (int t = 0; t < 8; t++) acc[t] = (f32x4){0.f, 0.f, 0.f, 0.f};
  accv[0] = (f32x4){0.f, 0.f, 0.f, 0.f};
  accv[1] = (f32x4){0.f, 0.f, 0.f, 0.f};

  const float* arow = obs + ((size_t)b * N_ + r0 + t16) * F_ + q * 8;
  const short* wta = (const short*)wt_act;
  const short* wtv = (const short*)wt_v1;

#pragma unroll 2
  for (int k0 = 0; k0 < F_; k0 += 32) {
    short8 a = load_bf16x8(arow + k0);
#pragma unroll
    for (int t = 0; t < 8; t++) {
      short8 bw = *(const short8*)(wta + (size_t)(t * 16 + t16) * F_ + k0 + q * 8);
      acc[t] = MFMA16(a, bw, acc[t]);
    }
#pragma unroll
    for (int t = 0; t < 2; t++) {
      short8 bw = *(const short8*)(wtv + (size_t)(t * 16 + t16) * F_ + k0 + q * 8);
      accv[t] = MFMA16(a, bw, accv[t]);
    }
  }

  // C/D layout: col = lane&15, row = q*4 + reg
  float hv[8][4];
  float s[4] = {0.f, 0.f, 0.f, 0.f};
#pragma unroll
  for (int t = 0; t < 8; t++) {
    int c = t * 16 + t16;
    float bias = b_act[c] + gen * W_act[(size_t)512 * HA_ + c];
#pragma unroll
    for (int r = 0; r < 4; r++) {
      float v = acc[t][r] + bias;
      hv[t][r] = v;
      s[r] += v * v;
    }
  }
#pragma unroll
  for (int m = 1; m < 16; m <<= 1) {
#pragma unroll
    for (int r = 0; r < 4; r++) s[r] += __shfl_xor(s[r], m, 64);
  }
#pragma unroll
  for (int r = 0; r < 4; r++) {
    float inv = 1.0f / fmaxf(sqrtf(s[r]), 1e-8f);
    int row = r0 + q * 4 + r;
    __hip_bfloat16* orow = hn + ((size_t)b * N_ + row) * HA_;
#pragma unroll
    for (int t = 0; t < 8; t++) {
      orow[t * 16 + t16] = __float2bfloat16(hv[t][r] * inv);
    }
  }

  // critic
  float vrow[4] = {0.f, 0.f, 0.f, 0.f};
#pragma unroll
  for (int t = 0; t < 2; t++) {
    int c = t * 16 + t16;
    float bias = b_v1[c] + gen * W_v1[(size_t)512 * HV_ + c];
    float w2 = W_v2[c];
#pragma unroll
    for (int r = 0; r < 4; r++) {
      float v = accv[t][r] + bias;
      v = v > 0.f ? v : 0.f;
      vrow[r] += v * w2;
    }
  }
#pragma unroll
  for (int m = 1; m < 16; m <<= 1) {
#pragma unroll
    for (int r = 0; r < 4; r++) vrow[r] += __shfl_xor(vrow[r], m, 64);
  }
  float bv2 = b_v2[0];
  float wsum = vrow[0] + vrow[1] + vrow[2] + vrow[3] + 4.f * bv2;
  wsum += __shfl_xor(wsum, 16, 64);
  wsum += __shfl_xor(wsum, 32, 64);
  if (lane == 0) atomicAdd(&critic_acc[b], wsum);
}

// ---------------- pairwise: out = -(hn @ hn^T), fp32 out ----------------
// grid (32 jTiles, 32 iTiles, 4 batches), 256 threads; 128x128 per block.
// Epilogue: stage each wave's 32x128 tile through wave-private LDS (padded
// 132-float rows), read back float4 so each wave store instruction writes
// 2 rows x 512 B fully contiguous (global_store_dwordx4, nontemporal).
__global__ __launch_bounds__(256) void k_pair(
    const __hip_bfloat16* __restrict__ hn,   // [4][4096][128] bf16
    const float* __restrict__ critic_acc,    // [4]
    float* __restrict__ out)                 // [4*4096*4096 + 4] fp32
{
  __shared__ float lds[4][16][132];  // per-wave 16x132 fp32, reused for rt=0,1

  const int wave = threadIdx.x >> 6;
  const int lane = threadIdx.x & 63;
  const int q = lane >> 4;
  const int t16 = lane & 15;
  const int b = blockIdx.z;
  const int i0 = blockIdx.y * 128 + wave * 32;
  const int j0 = blockIdx.x * 128;

  // fused critic finalize (k_hn completed before this launch, stream order)
  if (blockIdx.x == 0 && blockIdx.y == 0 && blockIdx.z == 0 &&
      threadIdx.x < B_) {
    out[(size_t)B_ * N_ * N_ + threadIdx.x] =
        critic_acc[threadIdx.x] / (float)N_;
  }

  const short* base = (const short*)hn + (size_t)b * N_ * HA_;

  f32x4 acc[2][8];
#pragma unroll
  for (int rt = 0; rt < 2; rt++)
#pragma unroll
    for (int ct = 0; ct < 8; ct++) acc[rt][ct] = (f32x4){0.f, 0.f, 0.f, 0.f};

#pragma unroll
  for (int k0 = 0; k0 < HA_; k0 += 32) {
    short8 a[2], bb[8];
#pragma unroll
    for (int rt = 0; rt < 2; rt++)
      a[rt] = *(const short8*)(base + (size_t)(i0 + rt * 16 + t16) * HA_ + k0 + q * 8);
#pragma unroll
    for (int ct = 0; ct < 8; ct++)
      bb[ct] = *(const short8*)(base + (size_t)(j0 + ct * 16 + t16) * HA_ + k0 + q * 8);
#pragma unroll
    for (int rt = 0; rt < 2; rt++)
#pragma unroll
      for (int ct = 0; ct < 8; ct++)
        acc[rt][ct] = MFMA16(a[rt], bb[ct], acc[rt][ct]);
  }

  // ---- epilogue: LDS-staged, vectorized nontemporal stores ----
  float* wl = &lds[wave][0][0];
#pragma unroll
  for (int rt = 0; rt < 2; rt++) {
    // scatter this 16x128 half-tile into padded LDS (2-way bank alias: free)
#pragma unroll
    for (int ct = 0; ct < 8; ct++) {
#pragma unroll
      for (int r = 0; r < 4; r++) {
        wl[(q * 4 + r) * 132 + ct * 16 + t16] = -acc[rt][ct][r];
      }
    }
    // gather back as float4: per instruction, wave writes 2 rows x 512 B
#pragma unroll
    for (int it = 0; it < 8; it++) {
      int row = 2 * it + (lane >> 5);
      int colf = (lane & 31) * 4;
      f32x4 v = *(const f32x4*)(wl + row * 132 + colf);
      size_t grow = (size_t)(i0 + rt * 16 + row);
      float* op = out + ((size_t)b * N_ + grow) * N_ + j0 + colf;
      __builtin_nontemporal_store(v, (f32x4*)op);
    }
  }
}

extern "C" void kernel_launch(void* const* d_in, const int* in_sizes, int n_in,
                              void* d_out, int out_size, void* d_ws, size_t ws_size,
                              hipStream_t stream) {
  const float* obs        = (const float*)d_in[0];
  const float* gen_number = (const float*)d_in[1];
  const float* W_gen      = (const float*)d_in[2];
  const float* b_gen      = (const float*)d_in[3];
  const float* W_act      = (const float*)d_in[4];
  const float* b_act      = (const float*)d_in[5];
  const float* W_v1       = (const float*)d_in[6];
  const float* b_v1       = (const float*)d_in[7];
  const float* W_v2       = (const float*)d_in[8];
  const float* b_v2       = (const float*)d_in[9];

  float* out = (float*)d_out;

  char* ws = (char*)d_ws;
  float* critic_acc      = (float*)ws;
  __hip_bfloat16* wt_act = (__hip_bfloat16*)(ws + OFF_WTA);
  __hip_bfloat16* wt_v1  = (__hip_bfloat16*)(ws + OFF_WTV);
  __hip_bfloat16* hn     = (__hip_bfloat16*)(ws + OFF_HN);

  hipMemsetAsync(critic_acc, 0, 16, stream);

  k_tr<<<320, 256, 0, stream>>>(W_act, W_v1, wt_act, wt_v1);

  k_hn<<<256, 256, 0, stream>>>(obs, gen_number, W_gen, b_gen, W_act, b_act,
                                W_v1, b_v1, W_v2, b_v2, wt_act, wt_v1, hn,
                                critic_acc);

  k_pair<<<dim3(32, 32, 4), 256, 0, stream>>>(hn, critic_acc, out);
}